// Round 1
// baseline (1005.971 us; speedup 1.0000x reference)
//
#include <hip/hip_runtime.h>

#define N_NODES 200000
#define N_EDGES 3200000
#define N_GRAPHS 1024
#define HD 16
#define ALPHA_ 0.2f

__global__ __launch_bounds__(256) void deg_kernel(const int* __restrict__ dst,
                                                  const float* __restrict__ ea,
                                                  float* __restrict__ deg) {
    int e = blockIdx.x * blockDim.x + threadIdx.x;
    if (e < N_EDGES) atomicAdd(&deg[dst[e]], ea[e]);
}

__global__ __launch_bounds__(256) void dinv_kernel(float* __restrict__ deg) {
    int n = blockIdx.x * blockDim.x + threadIdx.x;
    if (n < N_NODES) deg[n] = rsqrtf(deg[n] + 1.0f);
}

__global__ __launch_bounds__(256) void enorm_kernel(const int* __restrict__ src,
                                                    const int* __restrict__ dst,
                                                    const float* __restrict__ ea,
                                                    const float* __restrict__ dinv,
                                                    float* __restrict__ enorm) {
    int e = blockIdx.x * blockDim.x + threadIdx.x;
    if (e < N_EDGES) enorm[e] = dinv[src[e]] * ea[e] * dinv[dst[e]];
}

// layer 0: hW[n][j] = x[n] * cw0[j]   (1 -> 16)
__global__ __launch_bounds__(256) void hw0_kernel(const float* __restrict__ x,
                                                  const float* __restrict__ cw0,
                                                  float* __restrict__ hW) {
    int i = blockIdx.x * blockDim.x + threadIdx.x;
    if (i < N_NODES * HD) {
        int n = i >> 4, j = i & 15;
        hW[i] = x[n] * cw0[j];
    }
}

// out[n][:] = in[n][:] @ W   (16x16, no bias)
__global__ __launch_bounds__(256) void mat16_kernel(const float* __restrict__ in,
                                                    const float* __restrict__ W,
                                                    float* __restrict__ out) {
    __shared__ float sW[256];
    sW[threadIdx.x] = W[threadIdx.x];
    __syncthreads();
    int n = blockIdx.x * blockDim.x + threadIdx.x;
    if (n >= N_NODES) return;
    const float4* inr = (const float4*)(in + n * HD);
    float4 r0 = inr[0], r1 = inr[1], r2 = inr[2], r3 = inr[3];
    float a[16] = {r0.x, r0.y, r0.z, r0.w, r1.x, r1.y, r1.z, r1.w,
                   r2.x, r2.y, r2.z, r2.w, r3.x, r3.y, r3.z, r3.w};
    float acc[16];
#pragma unroll
    for (int j = 0; j < 16; ++j) acc[j] = 0.f;
#pragma unroll
    for (int k = 0; k < 16; ++k)
#pragma unroll
        for (int j = 0; j < 16; ++j) acc[j] += a[k] * sW[k * 16 + j];
    float4* o = (float4*)(out + n * HD);
    o[0] = make_float4(acc[0], acc[1], acc[2], acc[3]);
    o[1] = make_float4(acc[4], acc[5], acc[6], acc[7]);
    o[2] = make_float4(acc[8], acc[9], acc[10], acc[11]);
    o[3] = make_float4(acc[12], acc[13], acc[14], acc[15]);
}

// one thread per (edge, feature): agg[dst][j] += enorm[e] * hW[src][j]
__global__ __launch_bounds__(256) void edge_agg_kernel(const int* __restrict__ src,
                                                       const int* __restrict__ dst,
                                                       const float* __restrict__ enorm,
                                                       const float* __restrict__ hW,
                                                       float* __restrict__ agg) {
    unsigned int i = blockIdx.x * blockDim.x + threadIdx.x;
    if (i >= (unsigned)N_EDGES * HD) return;
    int e = i >> 4, j = i & 15;
    int s = src[e], d = dst[e];
    atomicAdd(&agg[d * HD + j], enorm[e] * hW[s * HD + j]);
}

// a = relu(agg + dinv^2*hW + cb);  h = a @ lw + lb
__global__ __launch_bounds__(256) void combine_linear_kernel(const float* __restrict__ agg,
                                                             const float* __restrict__ hW,
                                                             const float* __restrict__ dinv,
                                                             const float* __restrict__ cb_l,
                                                             const float* __restrict__ lw_l,
                                                             const float* __restrict__ lb_l,
                                                             float* __restrict__ h) {
    __shared__ float sW[256];
    __shared__ float sb[16];
    __shared__ float scb[16];
    sW[threadIdx.x] = lw_l[threadIdx.x];
    if (threadIdx.x < 16) {
        sb[threadIdx.x] = lb_l[threadIdx.x];
        scb[threadIdx.x] = cb_l[threadIdx.x];
    }
    __syncthreads();
    int n = blockIdx.x * blockDim.x + threadIdx.x;
    if (n >= N_NODES) return;
    float sn = dinv[n];
    sn *= sn;
    const float4* ar = (const float4*)(agg + n * HD);
    const float4* hr = (const float4*)(hW + n * HD);
    float4 a0 = ar[0], a1 = ar[1], a2 = ar[2], a3 = ar[3];
    float4 h0 = hr[0], h1 = hr[1], h2 = hr[2], h3 = hr[3];
    float ag[16] = {a0.x, a0.y, a0.z, a0.w, a1.x, a1.y, a1.z, a1.w,
                    a2.x, a2.y, a2.z, a2.w, a3.x, a3.y, a3.z, a3.w};
    float hw[16] = {h0.x, h0.y, h0.z, h0.w, h1.x, h1.y, h1.z, h1.w,
                    h2.x, h2.y, h2.z, h2.w, h3.x, h3.y, h3.z, h3.w};
    float a[16];
#pragma unroll
    for (int j = 0; j < 16; ++j)
        a[j] = fmaxf(ag[j] + sn * hw[j] + scb[j], 0.f);
    float acc[16];
#pragma unroll
    for (int j = 0; j < 16; ++j) acc[j] = sb[j];
#pragma unroll
    for (int k = 0; k < 16; ++k)
#pragma unroll
        for (int j = 0; j < 16; ++j) acc[j] += a[k] * sW[k * 16 + j];
    float4* o = (float4*)(h + n * HD);
    o[0] = make_float4(acc[0], acc[1], acc[2], acc[3]);
    o[1] = make_float4(acc[4], acc[5], acc[6], acc[7]);
    o[2] = make_float4(acc[8], acc[9], acc[10], acc[11]);
    o[3] = make_float4(acc[12], acc[13], acc[14], acc[15]);
}

// num[g][j] += h*exp(a*h); den[g][j] += exp(a*h)
__global__ __launch_bounds__(256) void pool_kernel(const float* __restrict__ h,
                                                   const int* __restrict__ batch,
                                                   float* __restrict__ num,
                                                   float* __restrict__ den) {
    int i = blockIdx.x * blockDim.x + threadIdx.x;
    if (i >= N_NODES * HD) return;
    int n = i >> 4, j = i & 15;
    float v = h[i];
    float s = expf(ALPHA_ * v);
    int g = batch[n];
    atomicAdd(&num[g * HD + j], v * s);
    atomicAdd(&den[g * HD + j], s);
}

__global__ __launch_bounds__(64) void final_kernel(const float* __restrict__ num,
                                                   const float* __restrict__ den,
                                                   const float* __restrict__ w1,
                                                   const float* __restrict__ b1,
                                                   const float* __restrict__ w2,
                                                   const float* __restrict__ b2,
                                                   const float* __restrict__ w3,
                                                   const float* __restrict__ b3,
                                                   float* __restrict__ out) {
    int g = blockIdx.x * blockDim.x + threadIdx.x;
    if (g >= N_GRAPHS) return;
    float p[16];
#pragma unroll
    for (int j = 0; j < 16; ++j) p[j] = num[g * HD + j] / den[g * HD + j];
    float t1[16];
#pragma unroll
    for (int j = 0; j < 16; ++j) {
        float acc = b1[j];
#pragma unroll
        for (int k = 0; k < 16; ++k) acc += p[k] * w1[k * 16 + j];
        t1[j] = fmaxf(acc, 0.f);
    }
    float t2[16];
#pragma unroll
    for (int j = 0; j < 16; ++j) {
        float acc = b2[j];
#pragma unroll
        for (int k = 0; k < 16; ++k) acc += t1[k] * w2[k * 16 + j];
        t2[j] = fmaxf(acc, 0.f);
    }
    float o = b3[0];
#pragma unroll
    for (int k = 0; k < 16; ++k) o += t2[k] * w3[k];
    out[g] = o;
}

extern "C" void kernel_launch(void* const* d_in, const int* in_sizes, int n_in,
                              void* d_out, int out_size, void* d_ws, size_t ws_size,
                              hipStream_t stream) {
    const float* x   = (const float*)d_in[0];
    const int*   ei  = (const int*)d_in[1];
    const int*   src = ei;
    const int*   dst = ei + N_EDGES;
    const int*   batch = (const int*)d_in[2];
    const float* ea  = (const float*)d_in[3];
    const float* cw0 = (const float*)d_in[4];
    const float* cwr = (const float*)d_in[5];
    const float* cb  = (const float*)d_in[6];
    const float* lw  = (const float*)d_in[7];
    const float* lb  = (const float*)d_in[8];
    const float* w1  = (const float*)d_in[9];
    const float* b1  = (const float*)d_in[10];
    const float* w2  = (const float*)d_in[11];
    const float* b2  = (const float*)d_in[12];
    const float* w3  = (const float*)d_in[13];
    const float* b3  = (const float*)d_in[14];
    float* out = (float*)d_out;

    // workspace layout (floats)
    float* ws    = (float*)d_ws;
    float* dinv  = ws;                         // N
    float* enorm = dinv + N_NODES;             // E
    float* hW    = enorm + N_EDGES;            // N*16
    float* agg   = hW + N_NODES * HD;          // N*16
    float* h     = agg + N_NODES * HD;         // N*16
    float* num   = h + N_NODES * HD;           // G*16
    float* den   = num + N_GRAPHS * HD;        // G*16

    const int TB = 256;
    int gE  = (N_EDGES + TB - 1) / TB;
    int gN  = (N_NODES + TB - 1) / TB;
    int gNH = (N_NODES * HD + TB - 1) / TB;
    int gEH = (int)(((unsigned)N_EDGES * HD + TB - 1) / TB);

    // degree + symmetric norm (reused across layers)
    hipMemsetAsync(dinv, 0, N_NODES * sizeof(float), stream);
    deg_kernel<<<gE, TB, 0, stream>>>(dst, ea, dinv);
    dinv_kernel<<<gN, TB, 0, stream>>>(dinv);
    enorm_kernel<<<gE, TB, 0, stream>>>(src, dst, ea, dinv, enorm);

    for (int l = 0; l < 3; ++l) {
        if (l == 0)
            hw0_kernel<<<gNH, TB, 0, stream>>>(x, cw0, hW);
        else
            mat16_kernel<<<gN, TB, 0, stream>>>(h, cwr + (l - 1) * 256, hW);
        hipMemsetAsync(agg, 0, (size_t)N_NODES * HD * sizeof(float), stream);
        edge_agg_kernel<<<gEH, TB, 0, stream>>>(src, dst, enorm, hW, agg);
        combine_linear_kernel<<<gN, TB, 0, stream>>>(agg, hW, dinv, cb + l * 16,
                                                     lw + l * 256, lb + l * 16, h);
    }

    hipMemsetAsync(num, 0, (size_t)2 * N_GRAPHS * HD * sizeof(float), stream);
    pool_kernel<<<gNH, TB, 0, stream>>>(h, batch, num, den);
    final_kernel<<<(N_GRAPHS + 63) / 64, 64, 0, stream>>>(num, den, w1, b1, w2, b2, w3, b3, out);
}

// Round 2
// 893.150 us; speedup vs baseline: 1.1263x; 1.1263x over previous
//
#include <hip/hip_runtime.h>

#define N_NODES 200000
#define N_EDGES 3200000
#define N_GRAPHS 1024
#define HD 16
#define ALPHA_ 0.2f
#define NB_SCAN 782  // ceil(N_NODES/256)

// fused weighted degree (float) + edge count (int) per dst node
__global__ __launch_bounds__(256) void deg_count_kernel(const int* __restrict__ dst,
                                                        const float* __restrict__ ea,
                                                        float* __restrict__ deg,
                                                        int* __restrict__ count) {
    int e = blockIdx.x * blockDim.x + threadIdx.x;
    if (e < N_EDGES) {
        int d = dst[e];
        atomicAdd(&count[d], 1);
        atomicAdd(&deg[d], ea[e]);
    }
}

__global__ __launch_bounds__(256) void dinv_kernel(float* __restrict__ deg) {
    int n = blockIdx.x * blockDim.x + threadIdx.x;
    if (n < N_NODES) deg[n] = rsqrtf(deg[n] + 1.0f);
}

// per-block partial sums of count
__global__ __launch_bounds__(256) void scan_part_kernel(const int* __restrict__ count,
                                                        int* __restrict__ partial) {
    __shared__ int s[256];
    int t = threadIdx.x;
    int n = blockIdx.x * 256 + t;
    s[t] = (n < N_NODES) ? count[n] : 0;
    __syncthreads();
#pragma unroll
    for (int off = 128; off > 0; off >>= 1) {
        if (t < off) s[t] += s[t + off];
        __syncthreads();
    }
    if (t == 0) partial[blockIdx.x] = s[0];
}

// exclusive scan of block partial sums (single block, one wave)
__global__ __launch_bounds__(64) void scan_block_kernel(int* __restrict__ partial, int nb) {
    int lane = threadIdx.x;
    int running = 0;
    for (int base = 0; base < nb; base += 64) {
        int i = base + lane;
        int orig = (i < nb) ? partial[i] : 0;
        int v = orig;
#pragma unroll
        for (int off = 1; off < 64; off <<= 1) {
            int u = __shfl_up(v, off);
            if (lane >= off) v += u;
        }
        int total = __shfl(v, 63);
        if (i < nb) partial[i] = v - orig + running;
        running += total;
    }
}

// offs[n] = partial[blk] + block-local exclusive scan; cursor initialized = offs
__global__ __launch_bounds__(256) void scan_final_kernel(const int* __restrict__ count,
                                                         const int* __restrict__ partial,
                                                         int* __restrict__ offs,
                                                         int* __restrict__ cursor) {
    __shared__ int s[256];
    int t = threadIdx.x;
    int n = blockIdx.x * 256 + t;
    int c = (n < N_NODES) ? count[n] : 0;
    s[t] = c;
    __syncthreads();
#pragma unroll
    for (int off = 1; off < 256; off <<= 1) {
        int v = (t >= off) ? s[t - off] : 0;
        __syncthreads();
        s[t] += v;
        __syncthreads();
    }
    if (n < N_NODES) {
        int o = partial[blockIdx.x] + s[t] - c;
        offs[n] = o;
        cursor[n] = o;
    }
}

// scatter edges into CSR order, computing enorm inline
__global__ __launch_bounds__(256) void scatter_kernel(const int* __restrict__ src,
                                                      const int* __restrict__ dst,
                                                      const float* __restrict__ ea,
                                                      const float* __restrict__ dinv,
                                                      int* __restrict__ cursor,
                                                      int* __restrict__ csr_src,
                                                      float* __restrict__ csr_w) {
    int e = blockIdx.x * blockDim.x + threadIdx.x;
    if (e >= N_EDGES) return;
    int s = src[e], d = dst[e];
    int pos = atomicAdd(&cursor[d], 1);
    csr_src[pos] = s;
    csr_w[pos] = dinv[s] * ea[e] * dinv[d];
}

// layer 0, exploiting rank-1 hW = x * cw0^T: scalar aggregation + outer product + linear
__global__ __launch_bounds__(256) void agg0_combine_kernel(const float* __restrict__ x,
                                                           const int* __restrict__ offs,
                                                           const int* __restrict__ count,
                                                           const int* __restrict__ csr_src,
                                                           const float* __restrict__ csr_w,
                                                           const float* __restrict__ dinv,
                                                           const float* __restrict__ cw0,
                                                           const float* __restrict__ cb0,
                                                           const float* __restrict__ lw0,
                                                           const float* __restrict__ lb0,
                                                           float* __restrict__ h) {
    __shared__ float sW[256];
    __shared__ float scw[16], scb[16], slb[16];
    int t = threadIdx.x;
    sW[t] = lw0[t];
    if (t < 16) { scw[t] = cw0[t]; scb[t] = cb0[t]; slb[t] = lb0[t]; }
    __syncthreads();
    int n = blockIdx.x * 256 + t;
    if (n >= N_NODES) return;
    float acc = 0.f;
    int beg = offs[n], cnt = count[n];
    for (int k = 0; k < cnt; ++k) {
        int s = csr_src[beg + k];
        acc += csr_w[beg + k] * x[s];
    }
    float sn = dinv[n];
    float base = acc + sn * sn * x[n];
    float a[16];
#pragma unroll
    for (int j = 0; j < 16; ++j) a[j] = fmaxf(base * scw[j] + scb[j], 0.f);
    float o[16];
#pragma unroll
    for (int j = 0; j < 16; ++j) o[j] = slb[j];
#pragma unroll
    for (int k = 0; k < 16; ++k)
#pragma unroll
        for (int j = 0; j < 16; ++j) o[j] += a[k] * sW[k * 16 + j];
    float4* op = (float4*)(h + n * HD);
    op[0] = make_float4(o[0], o[1], o[2], o[3]);
    op[1] = make_float4(o[4], o[5], o[6], o[7]);
    op[2] = make_float4(o[8], o[9], o[10], o[11]);
    op[3] = make_float4(o[12], o[13], o[14], o[15]);
}

// hW = h @ W  (16x16)
__global__ __launch_bounds__(256) void mat16_kernel(const float* __restrict__ in,
                                                    const float* __restrict__ W,
                                                    float* __restrict__ out) {
    __shared__ float sW[256];
    sW[threadIdx.x] = W[threadIdx.x];
    __syncthreads();
    int n = blockIdx.x * blockDim.x + threadIdx.x;
    if (n >= N_NODES) return;
    const float4* inr = (const float4*)(in + n * HD);
    float4 r0 = inr[0], r1 = inr[1], r2 = inr[2], r3 = inr[3];
    float a[16] = {r0.x, r0.y, r0.z, r0.w, r1.x, r1.y, r1.z, r1.w,
                   r2.x, r2.y, r2.z, r2.w, r3.x, r3.y, r3.z, r3.w};
    float acc[16];
#pragma unroll
    for (int j = 0; j < 16; ++j) acc[j] = 0.f;
#pragma unroll
    for (int k = 0; k < 16; ++k)
#pragma unroll
        for (int j = 0; j < 16; ++j) acc[j] += a[k] * sW[k * 16 + j];
    float4* o = (float4*)(out + n * HD);
    o[0] = make_float4(acc[0], acc[1], acc[2], acc[3]);
    o[1] = make_float4(acc[4], acc[5], acc[6], acc[7]);
    o[2] = make_float4(acc[8], acc[9], acc[10], acc[11]);
    o[3] = make_float4(acc[12], acc[13], acc[14], acc[15]);
}

// CSR gather-aggregate + combine + linear. Block = 16 nodes x 16 features.
__global__ __launch_bounds__(256) void agg_combine_kernel(const int* __restrict__ offs,
                                                          const int* __restrict__ count,
                                                          const int* __restrict__ csr_src,
                                                          const float* __restrict__ csr_w,
                                                          const float* __restrict__ hW,
                                                          const float* __restrict__ dinv,
                                                          const float* __restrict__ cb_l,
                                                          const float* __restrict__ lw_l,
                                                          const float* __restrict__ lb_l,
                                                          float* __restrict__ h) {
    __shared__ float sW[256];
    __shared__ float sb[16], scb[16];
    __shared__ float sa[16][17];
    int t = threadIdx.x;
    sW[t] = lw_l[t];
    if (t < 16) { sb[t] = lb_l[t]; scb[t] = cb_l[t]; }
    __syncthreads();
    int nl = t >> 4, j = t & 15;
    int n = blockIdx.x * 16 + nl;
    if (n < N_NODES) {
        float acc = 0.f;
        int beg = offs[n], cnt = count[n];
        for (int k = 0; k < cnt; ++k) {
            int s = csr_src[beg + k];
            acc += csr_w[beg + k] * hW[s * HD + j];
        }
        float sn = dinv[n];
        acc += sn * sn * hW[n * HD + j] + scb[j];
        sa[nl][j] = fmaxf(acc, 0.f);
    }
    __syncthreads();
    if (n >= N_NODES) return;
    float o = sb[j];
#pragma unroll
    for (int k = 0; k < 16; ++k) o += sa[nl][k] * sW[k * 16 + j];
    h[n * HD + j] = o;
}

// segmented pooling over sorted batch: per-thread contiguous run + flush on boundary
#define POOL_RUN 32
__global__ __launch_bounds__(256) void pool_kernel(const float* __restrict__ h,
                                                   const int* __restrict__ batch,
                                                   float* __restrict__ num,
                                                   float* __restrict__ den) {
    int t = threadIdx.x;
    int tg = t >> 4, j = t & 15;
    int n_start = blockIdx.x * (16 * POOL_RUN) + tg * POOL_RUN;
    float accn = 0.f, accd = 0.f;
    int cur = -1;
    for (int k = 0; k < POOL_RUN; ++k) {
        int n = n_start + k;
        if (n >= N_NODES) break;
        int g = batch[n];
        if (g != cur) {
            if (cur >= 0) {
                atomicAdd(&num[cur * HD + j], accn);
                atomicAdd(&den[cur * HD + j], accd);
            }
            cur = g;
            accn = 0.f;
            accd = 0.f;
        }
        float v = h[n * HD + j];
        float s = expf(ALPHA_ * v);
        accn += v * s;
        accd += s;
    }
    if (cur >= 0) {
        atomicAdd(&num[cur * HD + j], accn);
        atomicAdd(&den[cur * HD + j], accd);
    }
}

__global__ __launch_bounds__(64) void final_kernel(const float* __restrict__ num,
                                                   const float* __restrict__ den,
                                                   const float* __restrict__ w1,
                                                   const float* __restrict__ b1,
                                                   const float* __restrict__ w2,
                                                   const float* __restrict__ b2,
                                                   const float* __restrict__ w3,
                                                   const float* __restrict__ b3,
                                                   float* __restrict__ out) {
    int g = blockIdx.x * blockDim.x + threadIdx.x;
    if (g >= N_GRAPHS) return;
    float p[16];
#pragma unroll
    for (int j = 0; j < 16; ++j) p[j] = num[g * HD + j] / den[g * HD + j];
    float t1[16];
#pragma unroll
    for (int j = 0; j < 16; ++j) {
        float acc = b1[j];
#pragma unroll
        for (int k = 0; k < 16; ++k) acc += p[k] * w1[k * 16 + j];
        t1[j] = fmaxf(acc, 0.f);
    }
    float t2[16];
#pragma unroll
    for (int j = 0; j < 16; ++j) {
        float acc = b2[j];
#pragma unroll
        for (int k = 0; k < 16; ++k) acc += t1[k] * w2[k * 16 + j];
        t2[j] = fmaxf(acc, 0.f);
    }
    float o = b3[0];
#pragma unroll
    for (int k = 0; k < 16; ++k) o += t2[k] * w3[k];
    out[g] = o;
}

extern "C" void kernel_launch(void* const* d_in, const int* in_sizes, int n_in,
                              void* d_out, int out_size, void* d_ws, size_t ws_size,
                              hipStream_t stream) {
    const float* x   = (const float*)d_in[0];
    const int*   ei  = (const int*)d_in[1];
    const int*   src = ei;
    const int*   dst = ei + N_EDGES;
    const int*   batch = (const int*)d_in[2];
    const float* ea  = (const float*)d_in[3];
    const float* cw0 = (const float*)d_in[4];
    const float* cwr = (const float*)d_in[5];
    const float* cb  = (const float*)d_in[6];
    const float* lw  = (const float*)d_in[7];
    const float* lb  = (const float*)d_in[8];
    const float* w1  = (const float*)d_in[9];
    const float* b1  = (const float*)d_in[10];
    const float* w2  = (const float*)d_in[11];
    const float* b2  = (const float*)d_in[12];
    const float* w3  = (const float*)d_in[13];
    const float* b3  = (const float*)d_in[14];
    float* out = (float*)d_out;

    // workspace layout (4-byte units)
    float* ws     = (float*)d_ws;
    float* deg    = ws;                             // N (becomes dinv in-place)
    int*   count  = (int*)(ws + N_NODES);           // N
    int*   cursor = (int*)(ws + 2 * N_NODES);       // N
    float* num    = ws + 3 * N_NODES;               // G*16
    float* den    = num + N_GRAPHS * HD;            // G*16
    int*   offs   = (int*)(den + N_GRAPHS * HD);    // N
    int*   partial = offs + N_NODES;                // NB_SCAN (pad 784)
    int*   csr_src = partial + 784;                 // E
    float* csr_w  = (float*)(csr_src + N_EDGES);    // E
    float* hW     = csr_w + N_EDGES;                // N*16
    float* h      = hW + (size_t)N_NODES * HD;      // N*16

    const int TB = 256;
    int gE = (N_EDGES + TB - 1) / TB;          // 12500
    int gN = (N_NODES + TB - 1) / TB;          // 782
    int gA = (N_NODES + 15) / 16;              // 12500 (agg_combine: 16 nodes/block)
    int gP = (N_NODES + 16 * POOL_RUN - 1) / (16 * POOL_RUN);  // 391

    // zero: deg, count, cursor, num, den (contiguous)
    hipMemsetAsync(ws, 0, (size_t)(3 * N_NODES + 2 * N_GRAPHS * HD) * sizeof(float), stream);

    // CSR build (once, reused for 3 layers)
    deg_count_kernel<<<gE, TB, 0, stream>>>(dst, ea, deg, count);
    dinv_kernel<<<gN, TB, 0, stream>>>(deg);
    scan_part_kernel<<<gN, TB, 0, stream>>>(count, partial);
    scan_block_kernel<<<1, 64, 0, stream>>>(partial, NB_SCAN);
    scan_final_kernel<<<gN, TB, 0, stream>>>(count, partial, offs, cursor);
    scatter_kernel<<<gE, TB, 0, stream>>>(src, dst, ea, deg, cursor, csr_src, csr_w);

    // layer 0 (rank-1 fast path)
    agg0_combine_kernel<<<gN, TB, 0, stream>>>(x, offs, count, csr_src, csr_w, deg,
                                               cw0, cb, lw, lb, h);
    // layers 1, 2
    for (int l = 1; l < 3; ++l) {
        mat16_kernel<<<gN, TB, 0, stream>>>(h, cwr + (l - 1) * 256, hW);
        agg_combine_kernel<<<gA, TB, 0, stream>>>(offs, count, csr_src, csr_w, hW, deg,
                                                  cb + l * 16, lw + l * 256, lb + l * 16, h);
    }

    hipMemsetAsync(num, 0, (size_t)2 * N_GRAPHS * HD * sizeof(float), stream);
    pool_kernel<<<gP, TB, 0, stream>>>(h, batch, num, den);
    final_kernel<<<(N_GRAPHS + 63) / 64, 64, 0, stream>>>(num, den, w1, b1, w2, b2, w3, b3, out);
}